// Round 10
// baseline (115.139 us; speedup 1.0000x reference)
//
#include <hip/hip_runtime.h>

// Row-wise top-K(32) of relu(A), zero elsewhere. N=8192 fp32 per row.
// TWO kernels to decouple the write stream from selection (R8: three
// structurally different single-kernel variants all pinned at ~92 us with
// ideal traffic -> the in-block load->barrier->select->store serialization
// is the limiter, not traffic and not occupancy limits).
//
// K1 (select_zero): one 256-thread block per row.
//   - read A once (R4: 2nd stream kills L3 residency)
//   - zero burst issued right after the hist pass; ALL block barriers are
//     raw lgkmcnt(0)+s_barrier (LDS-only) so NO vmcnt drain ever blocks the
//     stores (R5: vm-drain after a store burst costs ~12 us) -> stores
//     retire with the wave, fully overlapped with selection.
//   - wave 0: cutoff bin + exact (val desc, col asc) rank boundary; writes
//     the exactly-K selected (val,col) pairs into the row's first 64 floats
//     (not zeroed by K1) + flag=0 in d_ws. Fallback rows: flag=1, dense emit.
// K2 (patch): one wave per row. flag==1 -> skip. Else read 32 pairs from
//   floats [0..63], vmcnt(0), zero [0..63], vmcnt(0), scatter the 32 values.
// If ws_size < 32 KB: proven R8 single-kernel path.

constexpr int N     = 8192;
constexpr int K     = 32;
constexpr int HB    = 1024;      // histogram bins
constexpr int CAP   = 512;       // candidate list capacity (expected ~186)
constexpr int SLOTS = CAP / 64;
constexpr int BB    = 128;       // compacted cutoff-bin entries
constexpr int BLOCK = 256;
constexpr int PSLOT = 4;
constexpr float TSPEC = 2.0f;    // bin(2.0): bits>>20 = 1024

typedef float f4 __attribute__((ext_vector_type(4)));

// LDS-only barrier: orders LDS ops across the block WITHOUT draining vmem.
__device__ __forceinline__ void lgkm_barrier() {
    asm volatile("s_waitcnt lgkmcnt(0)" ::: "memory");
    __builtin_amdgcn_s_barrier();
    asm volatile("" ::: "memory");
}

// Cutoff bin B (bin of the K-th largest) and G = count strictly above B,
// over hist[0..1024). 16 bins/lane, staggered reads (2 lanes/bank: free).
__device__ __forceinline__ bool find_cutoff16(const unsigned* hist, int lane,
                                              int& B, int& G) {
    unsigned s = 0;
    #pragma unroll
    for (int i = 0; i < 16; ++i)
        s += hist[lane * 16 + ((i + lane) & 15)];
    unsigned acc = s;                       // inclusive suffix sum over lanes
    #pragma unroll
    for (int off = 1; off < 64; off <<= 1) {
        unsigned t = __shfl_down(acc, off, 64);
        if (lane + off < 64) acc += t;
    }
    unsigned long long m = __ballot(acc >= (unsigned)K);
    if (m == 0ull) return false;
    int g = 63 - __clzll((long long)m);
    unsigned above = (g < 63) ? (unsigned)__shfl((int)acc, g + 1, 64) : 0u;
    unsigned h  = (lane < 16) ? hist[g * 16 + lane] : 0u;
    unsigned a2 = h;
    #pragma unroll
    for (int off = 1; off < 64; off <<= 1) {
        unsigned t = __shfl_down(a2, off, 64);
        if (lane + off < 64) a2 += t;
    }
    unsigned long long m2 = __ballot(above + a2 >= (unsigned)K);
    int bl = 63 - __clzll((long long)m2);
    B = g * 16 + bl;
    G = (int)(above + (unsigned)__shfl((int)a2, bl, 64)
                    - (unsigned)__shfl((int)h,  bl, 64));
    return true;
}

// ===================== K1: select + zero burst =====================
__global__ __launch_bounds__(BLOCK)
void select_zero_kernel(const float* __restrict__ A, float* __restrict__ Out,
                        int* __restrict__ flags) {
    const int row  = blockIdx.x;
    const int tid  = threadIdx.x;
    const int lane = tid & 63;
    const int wave = tid >> 6;

    __shared__ unsigned hist[HB];
    __shared__ float    cv[CAP];
    __shared__ int      cc[CAP];
    __shared__ float    bbv[BB];
    __shared__ int      bbc[BB];
    __shared__ unsigned ccnt;
    __shared__ int      fb;

    #pragma unroll
    for (int i = 0; i < HB / BLOCK; ++i) hist[tid + i * BLOCK] = 0u;
    if (tid == 0) { ccnt = 0u; fb = 0; }
    lgkm_barrier();                              // barrier 1 (LDS only)

    // ---- the ONLY global read of A on the fast path ----
    const f4* __restrict__ Arow = reinterpret_cast<const f4*>(A + (size_t)row * N);
    #pragma unroll
    for (int i = 0; i < 8; ++i) {
        f4 v = Arow[i * BLOCK + tid];
        #pragma unroll
        for (int c = 0; c < 4; ++c) {
            float f = v[c];
            if (f > TSPEC) {
                atomicAdd(&hist[(__float_as_uint(f) >> 20) - 1024], 1u);
                unsigned ix = atomicAdd(&ccnt, 1u);
                if (ix < CAP) { cv[ix] = f; cc[ix] = (i * BLOCK + tid) * 4 + c; }
            }
        }
    }

    // ---- zero burst: no downstream dependency, drains during selection ----
    __builtin_amdgcn_sched_barrier(0);           // keep stores after the loads
    f4* __restrict__ Orow4 = reinterpret_cast<f4*>(Out + (size_t)row * N);
    const f4 z = {0.0f, 0.0f, 0.0f, 0.0f};
    #pragma unroll
    for (int i = 0; i < 8; ++i) {
        const int q = i * BLOCK + tid;
        if (q >= 16)                             // chunks 0..15 = pairs region
            __builtin_nontemporal_store(z, Orow4 + q);
    }

    lgkm_barrier();                              // barrier 2 (LDS only)

    // ---- selection: WAVE 0 ONLY ----
    if (wave == 0) {
        int B, G;
        bool ok = find_cutoff16(hist, lane, B, G);
        const unsigned Call = ccnt;
        bool bad = (!ok) || (Call > (unsigned)CAP);
        float vR = __int_as_float(0x7f800000);
        int   cR = -1;
        int   R  = 0;
        if (!bad) {
            R = K - G;
            const int C = (int)Call;
            int total = 0;
            #pragma unroll
            for (int s = 0; s < SLOTS; ++s) {
                const int j = lane + s * 64;
                bool flag = false; float fv = 0.0f; int fc = 0;
                if (j < C) {
                    fv = cv[j];
                    if ((int)((__float_as_uint(fv) >> 20) - 1024) == B) {
                        flag = true; fc = cc[j];
                    }
                }
                unsigned long long m = __ballot(flag);
                if (flag) {
                    int pos = total + __popcll(m & ((1ull << lane) - 1ull));
                    if (pos < BB) { bbv[pos] = fv; bbc[pos] = fc; }
                }
                total += (int)__popcll(m);
            }
            if (total > BB) {
                bad = true;
            } else {
                const int T = total;
                float mv0 = -1.0f, mv1 = -1.0f; int mc0 = 0x7fffffff, mc1 = 0x7fffffff;
                if (lane      < T) { mv0 = bbv[lane];      mc0 = bbc[lane]; }
                if (lane + 64 < T) { mv1 = bbv[lane + 64]; mc1 = bbc[lane + 64]; }
                int r0 = 0, r1 = 0;
                for (int j = 0; j < T; ++j) {
                    const float vj = bbv[j];
                    const int   cj = bbc[j];
                    if (vj > mv0 || (vj == mv0 && cj < mc0)) r0++;
                    if (vj > mv1 || (vj == mv1 && cj < mc1)) r1++;
                }
                float bv = 0.0f; int bc = -1; bool found = false;
                if (lane      < T && r0 == R - 1) { bv = mv0; bc = mc0; found = true; }
                if (lane + 64 < T && r1 == R - 1) { bv = mv1; bc = mc1; found = true; }
                unsigned long long bm = __ballot(found);
                if (bm != 0ull) {
                    int src = (int)__ffsll((long long)bm) - 1;
                    vR = __shfl(bv, src, 64);
                    cR = __shfl(bc, src, 64);
                }
            }
        }
        if (bad) {
            if (lane == 0) fb = 1;
        } else {
            // write the exactly-K selected (val,col) pairs into floats [0..63]
            const int C = (int)Call;
            float2* __restrict__ Op2 = reinterpret_cast<float2*>(Out + (size_t)row * N);
            int nsel = 0;
            #pragma unroll
            for (int s = 0; s < SLOTS; ++s) {
                const int j = lane + s * 64;
                bool flag = false; float fv = 0.0f; int fc = 0;
                if (j < C) {
                    fv = cv[j]; fc = cc[j];
                    flag = (fv > vR) || (fv == vR && fc <= cR);
                }
                unsigned long long m = __ballot(flag);
                if (flag) {
                    int pos = nsel + __popcll(m & ((1ull << lane) - 1ull));
                    if (pos < K) {
                        float2 p; p.x = fv; p.y = __int_as_float(fc);
                        Op2[pos] = p;
                    }
                }
                nsel += (int)__popcll(m);
            }
            if (lane == 0) flags[row] = 0;
        }
    }
    lgkm_barrier();                              // barrier 3 (LDS only)
    if (!fb) return;                             // stores retire with the wave

    // ---- exact fallback (block-uniform; ~never for N(0,1) rows) ----
    asm volatile("s_waitcnt vmcnt(0)" ::: "memory");  // zero burst landed
    if (tid == 0) { flags[row] = 1; ccnt = 0u; }
    #pragma unroll
    for (int i = 0; i < HB / BLOCK; ++i) hist[tid + i * BLOCK] = 0u;
    __syncthreads();
    #pragma unroll
    for (int i = 0; i < 8; ++i) {
        f4 v = Arow[i * BLOCK + tid];
        #pragma unroll
        for (int c = 0; c < 4; ++c) {
            float f = v[c];
            if (f > 0.0f) atomicAdd(&hist[__float_as_uint(f) >> 21], 1u);
        }
    }
    __syncthreads();
    int B, G;
    if (!find_cutoff16(hist, lane, B, G)) { B = -1; G = 0; }
    if (B >= 0) {
        #pragma unroll
        for (int i = 0; i < 8; ++i) {
            f4 v = Arow[i * BLOCK + tid];
            #pragma unroll
            for (int c = 0; c < 4; ++c) {
                float f = v[c];
                if (f > 0.0f && (int)(__float_as_uint(f) >> 21) == B) {
                    unsigned ix = atomicAdd(&ccnt, 1u);
                    if (ix < CAP) { cv[ix] = f; cc[ix] = (i * BLOCK + tid) * 4 + c; }
                }
            }
        }
    }
    __syncthreads();

    float vR = 0.0f;                             // B == -1: keep all positives
    int   cR = -1;
    if (B >= 0) {
        const int R = K - G;
        const int C = (int)min(ccnt, (unsigned)CAP);
        float mv[SLOTS]; int mc[SLOTS]; int rk[SLOTS];
        #pragma unroll
        for (int s = 0; s < SLOTS; ++s) {
            const int j = lane + s * 64;
            if (j < C) { mv[s] = cv[j]; mc[s] = cc[j]; }
            else       { mv[s] = -1.0f; mc[s] = 0x7fffffff; }
            rk[s] = 0;
        }
        for (int j = 0; j < C; ++j) {
            const float vj = cv[j];
            const int   cj = cc[j];
            #pragma unroll
            for (int s = 0; s < SLOTS; ++s)
                if (vj > mv[s] || (vj == mv[s] && cj < mc[s])) rk[s]++;
        }
        float bv = 0.0f; int bc = -1; bool found = false;
        #pragma unroll
        for (int s = 0; s < SLOTS; ++s)
            if (lane + s * 64 < C && rk[s] == R - 1) { bv = mv[s]; bc = mc[s]; found = true; }
        vR = __int_as_float(0x7f800000);
        unsigned long long bm = __ballot(found);
        if (bm != 0ull) {
            int src = (int)__ffsll((long long)bm) - 1;
            vR = __shfl(bv, src, 64);
            cR = __shfl(bc, src, 64);
        }
    }
    // dense emit: every chunk rewritten (zero stores already acked above)
    #pragma unroll
    for (int i = 0; i < 8; ++i) {
        f4 v = Arow[i * BLOCK + tid];
        f4 w;
        #pragma unroll
        for (int c = 0; c < 4; ++c) {
            float f   = v[c];
            int   col = (i * BLOCK + tid) * 4 + c;
            w[c] = ((f > vR) || (f == vR && col <= cR)) ? f : 0.0f;
        }
        __builtin_nontemporal_store(w, Orow4 + i * BLOCK + tid);
    }
}

// ===================== K2: patch the pairs region =====================
__global__ __launch_bounds__(BLOCK)
void patch_kernel(float* __restrict__ Out, const int* __restrict__ flags) {
    const int row  = (blockIdx.x * BLOCK + threadIdx.x) >> 6;  // one wave/row
    const int lane = threadIdx.x & 63;
    if (flags[row]) return;                      // fallback row: already dense
    float* __restrict__ Orow = Out + (size_t)row * N;
    float val = 0.0f; int col = 0;
    if (lane < K) {
        float2 p = reinterpret_cast<const float2*>(Orow)[lane];
        val = p.x; col = __float_as_int(p.y);
    }
    asm volatile("s_waitcnt vmcnt(0)" ::: "memory");   // pair reads landed
    Orow[lane] = 0.0f;                                 // zero floats [0..63]
    asm volatile("s_waitcnt vmcnt(0)" ::: "memory");   // zeros landed
    if (lane < K) Orow[col] = val;                     // scatter K values
}

// ============== guard path (ws too small): R8 single kernel ==============
struct Patches { float pval[PSLOT][BLOCK]; int pcol[PSLOT][BLOCK]; };
union USpace { unsigned hist[HB]; Patches p; };

__global__ __launch_bounds__(BLOCK)
void topk_relu_single(const float* __restrict__ A, float* __restrict__ Out) {
    const int row  = blockIdx.x;
    const int tid  = threadIdx.x;
    const int lane = tid & 63;
    const int wave = tid >> 6;
    __shared__ USpace   u;
    __shared__ float    cv[CAP];
    __shared__ int      cc[CAP];
    __shared__ float    bbv[BB];
    __shared__ int      bbc[BB];
    __shared__ unsigned pcnt[BLOCK];
    __shared__ unsigned ccnt;
    __shared__ int      fb;
    #pragma unroll
    for (int i = 0; i < HB / BLOCK; ++i) u.hist[tid + i * BLOCK] = 0u;
    pcnt[tid] = 0u;
    if (tid == 0) { ccnt = 0u; fb = 0; }
    __syncthreads();
    const f4* __restrict__ Arow = reinterpret_cast<const f4*>(A + (size_t)row * N);
    #pragma unroll
    for (int i = 0; i < 8; ++i) {
        f4 v = Arow[i * BLOCK + tid];
        #pragma unroll
        for (int c = 0; c < 4; ++c) {
            float f = v[c];
            if (f > TSPEC) {
                atomicAdd(&u.hist[(__float_as_uint(f) >> 20) - 1024], 1u);
                unsigned ix = atomicAdd(&ccnt, 1u);
                if (ix < CAP) { cv[ix] = f; cc[ix] = (i * BLOCK + tid) * 4 + c; }
            }
        }
    }
    __syncthreads();
    f4* __restrict__ Orow4 = reinterpret_cast<f4*>(Out + (size_t)row * N);
    if (wave == 0) {
        int B, G;
        bool ok = find_cutoff16(u.hist, lane, B, G);
        const unsigned Call = ccnt;
        if (!ok || Call > (unsigned)CAP) { fb = 1; }
        else {
            const int R = K - G;
            const int C = (int)Call;
            int total = 0;
            #pragma unroll
            for (int s = 0; s < SLOTS; ++s) {
                const int j = lane + s * 64;
                bool flag = false; float fv = 0.0f; int fc = 0;
                if (j < C) {
                    fv = cv[j];
                    if ((int)((__float_as_uint(fv) >> 20) - 1024) == B) { flag = true; fc = cc[j]; }
                }
                unsigned long long m = __ballot(flag);
                if (flag) {
                    int pos = total + __popcll(m & ((1ull << lane) - 1ull));
                    if (pos < BB) { bbv[pos] = fv; bbc[pos] = fc; }
                }
                total += (int)__popcll(m);
            }
            if (total > BB) { fb = 1; }
            else {
                const int T = total;
                float mv0 = -1.0f, mv1 = -1.0f; int mc0 = 0x7fffffff, mc1 = 0x7fffffff;
                if (lane      < T) { mv0 = bbv[lane];      mc0 = bbc[lane]; }
                if (lane + 64 < T) { mv1 = bbv[lane + 64]; mc1 = bbc[lane + 64]; }
                int r0 = 0, r1 = 0;
                for (int j = 0; j < T; ++j) {
                    const float vj = bbv[j]; const int cj = bbc[j];
                    if (vj > mv0 || (vj == mv0 && cj < mc0)) r0++;
                    if (vj > mv1 || (vj == mv1 && cj < mc1)) r1++;
                }
                float bv = 0.0f; int bc = -1; bool found = false;
                if (lane      < T && r0 == R - 1) { bv = mv0; bc = mc0; found = true; }
                if (lane + 64 < T && r1 == R - 1) { bv = mv1; bc = mc1; found = true; }
                float vR = __int_as_float(0x7f800000); int cR = -1;
                unsigned long long bm = __ballot(found);
                if (bm != 0ull) {
                    int src = (int)__ffsll((long long)bm) - 1;
                    vR = __shfl(bv, src, 64); cR = __shfl(bc, src, 64);
                }
                #pragma unroll
                for (int s = 0; s < SLOTS; ++s) {
                    const int j = lane + s * 64;
                    if (j < C) {
                        float fv = cv[j]; int fc = cc[j];
                        if (fv > vR || (fv == vR && fc <= cR)) {
                            int owner = (fc >> 2) & (BLOCK - 1);
                            unsigned p = atomicAdd(&pcnt[owner], 1u);
                            if (p < (unsigned)PSLOT) { u.p.pval[p][owner] = fv; u.p.pcol[p][owner] = fc; }
                            else fb = 1;
                        }
                    }
                }
            }
        }
    }
    __syncthreads();
    if (!fb) {
        const unsigned cnt = pcnt[tid];
        const float v0 = u.p.pval[0][tid], v1 = u.p.pval[1][tid],
                    v2 = u.p.pval[2][tid], v3 = u.p.pval[3][tid];
        const int   c0 = u.p.pcol[0][tid], c1 = u.p.pcol[1][tid],
                    c2 = u.p.pcol[2][tid], c3 = u.p.pcol[3][tid];
        unsigned m8 = 0;
        if (cnt > 0) m8 |= 1u << (c0 >> 10);
        if (cnt > 1) m8 |= 1u << (c1 >> 10);
        if (cnt > 2) m8 |= 1u << (c2 >> 10);
        if (cnt > 3) m8 |= 1u << (c3 >> 10);
        #pragma unroll
        for (int i = 0; i < 8; ++i) {
            f4 w = {0.0f, 0.0f, 0.0f, 0.0f};
            if (m8 & (1u << i)) {
                #define APPLY(CC, VV, KI)                                          \
                    if (cnt > (KI) && ((CC) >> 10) == i) {                         \
                        const int cm = (CC) & 3;                                   \
                        w[0] = (cm == 0) ? (VV) : w[0];                            \
                        w[1] = (cm == 1) ? (VV) : w[1];                            \
                        w[2] = (cm == 2) ? (VV) : w[2];                            \
                        w[3] = (cm == 3) ? (VV) : w[3];                            \
                    }
                APPLY(c0, v0, 0) APPLY(c1, v1, 1) APPLY(c2, v2, 2) APPLY(c3, v3, 3)
                #undef APPLY
            }
            __builtin_nontemporal_store(w, Orow4 + i * BLOCK + tid);
        }
        return;
    }
    #pragma unroll
    for (int i = 0; i < HB / BLOCK; ++i) u.hist[tid + i * BLOCK] = 0u;
    if (tid == 0) ccnt = 0u;
    __syncthreads();
    #pragma unroll
    for (int i = 0; i < 8; ++i) {
        f4 v = Arow[i * BLOCK + tid];
        #pragma unroll
        for (int c = 0; c < 4; ++c) {
            float f = v[c];
            if (f > 0.0f) atomicAdd(&u.hist[__float_as_uint(f) >> 21], 1u);
        }
    }
    __syncthreads();
    int B, G;
    if (!find_cutoff16(u.hist, lane, B, G)) { B = -1; G = 0; }
    if (B >= 0) {
        #pragma unroll
        for (int i = 0; i < 8; ++i) {
            f4 v = Arow[i * BLOCK + tid];
            #pragma unroll
            for (int c = 0; c < 4; ++c) {
                float f = v[c];
                if (f > 0.0f && (int)(__float_as_uint(f) >> 21) == B) {
                    unsigned ix = atomicAdd(&ccnt, 1u);
                    if (ix < CAP) { cv[ix] = f; cc[ix] = (i * BLOCK + tid) * 4 + c; }
                }
            }
        }
    }
    __syncthreads();
    float vR = 0.0f; int cR = -1;
    if (B >= 0) {
        const int R = K - G;
        const int C = (int)min(ccnt, (unsigned)CAP);
        float mv[SLOTS]; int mc[SLOTS]; int rk[SLOTS];
        #pragma unroll
        for (int s = 0; s < SLOTS; ++s) {
            const int j = lane + s * 64;
            if (j < C) { mv[s] = cv[j]; mc[s] = cc[j]; }
            else       { mv[s] = -1.0f; mc[s] = 0x7fffffff; }
            rk[s] = 0;
        }
        for (int j = 0; j < C; ++j) {
            const float vj = cv[j]; const int cj = cc[j];
            #pragma unroll
            for (int s = 0; s < SLOTS; ++s)
                if (vj > mv[s] || (vj == mv[s] && cj < mc[s])) rk[s]++;
        }
        float bv = 0.0f; int bc = -1; bool found = false;
        #pragma unroll
        for (int s = 0; s < SLOTS; ++s)
            if (lane + s * 64 < C && rk[s] == R - 1) { bv = mv[s]; bc = mc[s]; found = true; }
        vR = __int_as_float(0x7f800000);
        unsigned long long bm = __ballot(found);
        if (bm != 0ull) {
            int src = (int)__ffsll((long long)bm) - 1;
            vR = __shfl(bv, src, 64); cR = __shfl(bc, src, 64);
        }
    }
    #pragma unroll
    for (int i = 0; i < 8; ++i) {
        f4 v = Arow[i * BLOCK + tid];
        f4 w;
        #pragma unroll
        for (int c = 0; c < 4; ++c) {
            float f = v[c]; int col = (i * BLOCK + tid) * 4 + c;
            w[c] = ((f > vR) || (f == vR && col <= cR)) ? f : 0.0f;
        }
        __builtin_nontemporal_store(w, Orow4 + i * BLOCK + tid);
    }
}

extern "C" void kernel_launch(void* const* d_in, const int* in_sizes, int n_in,
                              void* d_out, int out_size, void* d_ws, size_t ws_size,
                              hipStream_t stream) {
    const float* A   = (const float*)d_in[0];
    float*       Out = (float*)d_out;
    (void)in_sizes; (void)n_in; (void)out_size;
    if (ws_size >= (size_t)N * sizeof(int)) {
        int* flags = (int*)d_ws;
        select_zero_kernel<<<dim3(N), dim3(BLOCK), 0, stream>>>(A, Out, flags);
        patch_kernel<<<dim3(N / 4), dim3(BLOCK), 0, stream>>>(Out, flags);
    } else {
        topk_relu_single<<<dim3(N), dim3(BLOCK), 0, stream>>>(A, Out);
    }
}